// Round 1
// baseline (2569.750 us; speedup 1.0000x reference)
//
#include <hip/hip_runtime.h>
#include <hip/hip_bf16.h>

#define N_NODES   100000
#define N_EDGES   1250000
#define N_GRAPHS  512
#define HIDDEN    64
#define F_IN      3
#define N_CLASSES 5

// ---------------------------------------------------------------------------
// 1) degree count on dst (self-loop added later as +1)
__global__ void k_deg(const int* __restrict__ dst, int* __restrict__ cnt) {
    int i = blockIdx.x * blockDim.x + threadIdx.x;
    if (i < N_EDGES) atomicAdd(&cnt[dst[i]], 1);
}

// 2) dis[i] = 1/sqrt(deg+1)
__global__ void k_dis(const int* __restrict__ cnt, float* __restrict__ dis) {
    int i = blockIdx.x * blockDim.x + threadIdx.x;
    if (i < N_NODES) dis[i] = rsqrtf((float)cnt[i] + 1.0f);
}

// 3) A = x @ W1   (x: [N,3], W1: [3,64])
__global__ void k_xw1(const float* __restrict__ x, const float* __restrict__ W1,
                      float* __restrict__ A) {
    int t = blockIdx.x * blockDim.x + threadIdx.x;   // n*64 + h
    if (t >= N_NODES * HIDDEN) return;
    int n = t >> 6, h = t & 63;
    float x0 = x[n * 3 + 0], x1 = x[n * 3 + 1], x2 = x[n * 3 + 2];
    A[t] = x0 * W1[h] + x1 * W1[HIDDEN + h] + x2 * W1[2 * HIDDEN + h];
}

// 4) edge scatter: AGG[dst] += H[src] * dis[src]*dis[dst]
//    one thread per (edge, quad-of-4-hidden): float4 gather + 4 atomics
__global__ void k_edge_agg(const int* __restrict__ src, const int* __restrict__ dst,
                           const float* __restrict__ dis,
                           const float* __restrict__ H, float* __restrict__ AGG) {
    int t = blockIdx.x * blockDim.x + threadIdx.x;   // e*16 + q
    if (t >= N_EDGES * 16) return;
    int e = t >> 4, q = t & 15;
    int s = src[e], d = dst[e];
    float norm = dis[s] * dis[d];
    float4 v = ((const float4*)(H + (size_t)s * HIDDEN))[q];
    float* o = AGG + (size_t)d * HIDDEN + q * 4;
    atomicAdd(o + 0, v.x * norm);
    atomicAdd(o + 1, v.y * norm);
    atomicAdd(o + 2, v.z * norm);
    atomicAdd(o + 3, v.w * norm);
}

// 5) combine: AGG = (maybe relu)(AGG + HW*dis^2 + b)
template <bool RELU>
__global__ void k_combine(const float* __restrict__ HW, const float* __restrict__ b,
                          const float* __restrict__ dis, float* __restrict__ AGG) {
    int t = blockIdx.x * blockDim.x + threadIdx.x;   // n*64 + h
    if (t >= N_NODES * HIDDEN) return;
    int n = t >> 6, h = t & 63;
    float di = dis[n];
    float v = AGG[t] + HW[t] * (di * di) + b[h];
    AGG[t] = RELU ? fmaxf(v, 0.0f) : v;
}

// 6) OUT = H @ W2   (H: [N,64], W2: [64,64]), W2 staged in LDS
__global__ void k_hw2(const float* __restrict__ H, const float* __restrict__ W2,
                      float* __restrict__ OUT) {
    __shared__ float w[HIDDEN * HIDDEN];
    for (int i = threadIdx.x; i < HIDDEN * HIDDEN; i += blockDim.x) w[i] = W2[i];
    __syncthreads();
    int t = blockIdx.x * blockDim.x + threadIdx.x;   // n*64 + h
    if (t >= N_NODES * HIDDEN) return;
    int n = t >> 6, h = t & 63;
    const float* hn = H + (size_t)n * HIDDEN;
    float acc = 0.0f;
#pragma unroll
    for (int k = 0; k < HIDDEN; k++) acc = fmaf(hn[k], w[k * HIDDEN + h], acc);
    OUT[t] = acc;
}

// 7) pooling sums + counts
__global__ void k_pool(const float* __restrict__ H2, const int* __restrict__ batch,
                       float* __restrict__ gsum, int* __restrict__ gcnt) {
    int t = blockIdx.x * blockDim.x + threadIdx.x;   // n*64 + h
    if (t >= N_NODES * HIDDEN) return;
    int n = t >> 6, h = t & 63;
    int g = batch[n];
    atomicAdd(&gsum[g * HIDDEN + h], H2[t]);
    if (h == 0) atomicAdd(&gcnt[g], 1);
}

// 8) out[g,c] = (gsum[g,:] @ Wl[:,c]) / max(cnt,1) + bl[c]
__global__ void k_final(const float* __restrict__ gsum, const int* __restrict__ gcnt,
                        const float* __restrict__ Wl, const float* __restrict__ bl,
                        float* __restrict__ out) {
    int t = blockIdx.x * blockDim.x + threadIdx.x;   // g*5 + c
    if (t >= N_GRAPHS * N_CLASSES) return;
    int g = t / N_CLASSES, c = t % N_CLASSES;
    float cnt = fmaxf((float)gcnt[g], 1.0f);
    float acc = 0.0f;
#pragma unroll
    for (int k = 0; k < HIDDEN; k++) acc = fmaf(gsum[g * HIDDEN + k], Wl[k * N_CLASSES + c], acc);
    out[t] = acc / cnt + bl[c];
}

// ---------------------------------------------------------------------------
extern "C" void kernel_launch(void* const* d_in, const int* in_sizes, int n_in,
                              void* d_out, int out_size, void* d_ws, size_t ws_size,
                              hipStream_t stream) {
    const float* x     = (const float*)d_in[0];
    const int*   ei    = (const int*)  d_in[1];   // [2, N_EDGES] flat: src then dst
    const int*   batch = (const int*)  d_in[2];
    const float* W1    = (const float*)d_in[3];
    const float* b1    = (const float*)d_in[4];
    const float* W2    = (const float*)d_in[5];
    const float* b2    = (const float*)d_in[6];
    const float* Wl    = (const float*)d_in[7];
    const float* bl    = (const float*)d_in[8];
    float* out = (float*)d_out;

    const int* src = ei;
    const int* dst = ei + N_EDGES;

    // workspace layout (floats)
    float* ws   = (float*)d_ws;
    float* dis  = ws;                                   // N
    int*   cnt  = (int*)(ws + N_NODES);                 // N
    float* A    = ws + 2 * N_NODES;                     // N*64  (XW / HW)
    float* B    = A + (size_t)N_NODES * HIDDEN;         // N*64  (agg1 -> h1)
    float* C    = B + (size_t)N_NODES * HIDDEN;         // N*64  (agg2 -> h2)
    float* gsum = C + (size_t)N_NODES * HIDDEN;         // 512*64
    int*   gcnt = (int*)(gsum + N_GRAPHS * HIDDEN);     // 512

    const int BS = 256;
    const int g_edges = (N_EDGES + BS - 1) / BS;
    const int g_nodes = (N_NODES + BS - 1) / BS;
    const int g_nh    = (N_NODES * HIDDEN + BS - 1) / BS;
    const int g_eq    = (N_EDGES * 16 + BS - 1) / BS;

    // degree + norm
    hipMemsetAsync(cnt, 0, N_NODES * sizeof(int), stream);
    k_deg<<<g_edges, BS, 0, stream>>>(dst, cnt);
    k_dis<<<g_nodes, BS, 0, stream>>>(cnt, dis);

    // layer 1
    k_xw1<<<g_nh, BS, 0, stream>>>(x, W1, A);
    hipMemsetAsync(B, 0, (size_t)N_NODES * HIDDEN * sizeof(float), stream);
    k_edge_agg<<<g_eq, BS, 0, stream>>>(src, dst, dis, A, B);
    k_combine<true><<<g_nh, BS, 0, stream>>>(A, b1, dis, B);   // B = h1

    // layer 2
    k_hw2<<<g_nh, BS, 0, stream>>>(B, W2, A);                  // A = h1@W2
    hipMemsetAsync(C, 0, (size_t)N_NODES * HIDDEN * sizeof(float), stream);
    k_edge_agg<<<g_eq, BS, 0, stream>>>(src, dst, dis, A, C);
    k_combine<false><<<g_nh, BS, 0, stream>>>(A, b2, dis, C);  // C = h2

    // pooling + head
    hipMemsetAsync(gsum, 0, N_GRAPHS * HIDDEN * sizeof(float), stream);
    hipMemsetAsync(gcnt, 0, N_GRAPHS * sizeof(int), stream);
    k_pool<<<g_nh, BS, 0, stream>>>(C, batch, gsum, gcnt);
    k_final<<<(N_GRAPHS * N_CLASSES + BS - 1) / BS, BS, 0, stream>>>(gsum, gcnt, Wl, bl, out);
}

// Round 2
// 531.325 us; speedup vs baseline: 4.8365x; 4.8365x over previous
//
#include <hip/hip_runtime.h>
#include <hip/hip_bf16.h>

#define N_NODES   100000
#define N_EDGES   1250000
#define N_GRAPHS  512
#define HIDDEN    64
#define F_IN      3
#define N_CLASSES 5

#define NBLK256   ((N_NODES + 255) / 256)   // 391 scan blocks

// ---------------------------------------------------------------------------
// 1) degree histogram on dst (self-loop added later as +1)
__global__ void k_deg(const int* __restrict__ dst, int* __restrict__ cnt) {
    int i = blockIdx.x * blockDim.x + threadIdx.x;
    if (i < N_EDGES) atomicAdd(&cnt[dst[i]], 1);
}

// 2) dis[i] = 1/sqrt(deg+1)
__global__ void k_dis(const int* __restrict__ cnt, float* __restrict__ dis) {
    int i = blockIdx.x * blockDim.x + threadIdx.x;
    if (i < N_NODES) dis[i] = rsqrtf((float)cnt[i] + 1.0f);
}

// --- 3-kernel exclusive scan of cnt -> rowptr --------------------------------
__global__ void k_scan_local(const int* __restrict__ cnt, int* __restrict__ rp,
                             int* __restrict__ bsum) {
    __shared__ int s[256];
    int i = blockIdx.x * 256 + threadIdx.x;
    int v = (i < N_NODES) ? cnt[i] : 0;
    s[threadIdx.x] = v;
    __syncthreads();
    for (int off = 1; off < 256; off <<= 1) {
        int t = (threadIdx.x >= off) ? s[threadIdx.x - off] : 0;
        __syncthreads();
        s[threadIdx.x] += t;
        __syncthreads();
    }
    if (i < N_NODES) rp[i] = s[threadIdx.x] - v;           // exclusive
    if (threadIdx.x == 255) bsum[blockIdx.x] = s[255];     // block total
}

__global__ void k_scan_bsum(int* __restrict__ bsum) {      // 1 block, 512 thr
    __shared__ int s[512];
    int v = (threadIdx.x < NBLK256) ? bsum[threadIdx.x] : 0;
    s[threadIdx.x] = v;
    __syncthreads();
    for (int off = 1; off < 512; off <<= 1) {
        int t = (threadIdx.x >= off) ? s[threadIdx.x - off] : 0;
        __syncthreads();
        s[threadIdx.x] += t;
        __syncthreads();
    }
    if (threadIdx.x < NBLK256) bsum[threadIdx.x] = s[threadIdx.x] - v; // exclusive
}

__global__ void k_scan_add(int* __restrict__ rp, const int* __restrict__ bsum,
                           int* __restrict__ cursor) {
    int i = blockIdx.x * 256 + threadIdx.x;
    if (i < N_NODES) {
        int v = rp[i] + bsum[blockIdx.x];
        rp[i] = v;
        cursor[i] = v;
    }
}

// 4) scatter edges into CSR: elist[pos] = src, grouped by dst
__global__ void k_fill(const int* __restrict__ src, const int* __restrict__ dst,
                       int* __restrict__ cursor, int* __restrict__ elist) {
    int e = blockIdx.x * blockDim.x + threadIdx.x;
    if (e < N_EDGES) {
        int pos = atomicAdd(&cursor[dst[e]], 1);
        elist[pos] = src[e];
    }
}

// 5) A = x @ W1   (x: [N,3], W1: [3,64])
__global__ void k_xw1(const float* __restrict__ x, const float* __restrict__ W1,
                      float* __restrict__ A) {
    int t = blockIdx.x * blockDim.x + threadIdx.x;   // n*64 + h
    if (t >= N_NODES * HIDDEN) return;
    int n = t >> 6, h = t & 63;
    float x0 = x[n * 3 + 0], x1 = x[n * 3 + 1], x2 = x[n * 3 + 2];
    A[t] = x0 * W1[h] + x1 * W1[HIDDEN + h] + x2 * W1[2 * HIDDEN + h];
}

// 6) gather aggregation, wave per node, lane = hidden channel.
//    OUT[n] = act( dis[n]*sum_{s in N(n)} HW[s]*dis[s] + HW[n]*dis[n]^2 + b )
template <bool RELU>
__global__ void k_gather(const int* __restrict__ rp, const int* __restrict__ cnt,
                         const int* __restrict__ elist, const float* __restrict__ dis,
                         const float* __restrict__ HW, const float* __restrict__ b,
                         float* __restrict__ OUT) {
    int node = blockIdx.x * 4 + (threadIdx.x >> 6);
    int lane = threadIdx.x & 63;
    if (node >= N_NODES) return;
    int start = rp[node];
    int deg   = cnt[node];
    float dn  = dis[node];
    float acc = 0.0f;
    for (int base = 0; base < deg; base += 64) {
        int m = min(64, deg - base);
        int eid = (lane < m) ? elist[start + base + lane] : 0;  // coalesced batch of ids
        int k = 0;
        for (; k + 4 <= m; k += 4) {                            // 4 gathers in flight
            int s0 = __shfl(eid, k);
            int s1 = __shfl(eid, k + 1);
            int s2 = __shfl(eid, k + 2);
            int s3 = __shfl(eid, k + 3);
            float w0 = dis[s0], w1 = dis[s1], w2 = dis[s2], w3 = dis[s3];
            float v0 = HW[(size_t)s0 * HIDDEN + lane];
            float v1 = HW[(size_t)s1 * HIDDEN + lane];
            float v2 = HW[(size_t)s2 * HIDDEN + lane];
            float v3 = HW[(size_t)s3 * HIDDEN + lane];
            acc += v0 * w0 + v1 * w1 + v2 * w2 + v3 * w3;
        }
        for (; k < m; k++) {
            int s0 = __shfl(eid, k);
            acc += HW[(size_t)s0 * HIDDEN + lane] * dis[s0];
        }
    }
    float v = acc * dn + HW[(size_t)node * HIDDEN + lane] * (dn * dn) + b[lane];
    OUT[(size_t)node * HIDDEN + lane] = RELU ? fmaxf(v, 0.0f) : v;
}

// 7) OUT = H @ W2   (H: [N,64], W2: [64,64]), W2 staged in LDS
__global__ void k_hw2(const float* __restrict__ H, const float* __restrict__ W2,
                      float* __restrict__ OUT) {
    __shared__ float w[HIDDEN * HIDDEN];
    for (int i = threadIdx.x; i < HIDDEN * HIDDEN; i += blockDim.x) w[i] = W2[i];
    __syncthreads();
    int t = blockIdx.x * blockDim.x + threadIdx.x;   // n*64 + h
    if (t >= N_NODES * HIDDEN) return;
    int n = t >> 6, h = t & 63;
    const float* hn = H + (size_t)n * HIDDEN;
    float acc = 0.0f;
#pragma unroll
    for (int k = 0; k < HIDDEN; k++) acc = fmaf(hn[k], w[k * HIDDEN + h], acc);
    OUT[t] = acc;
}

// 8) pooling: batch is SORTED -> wave walks contiguous node range,
//    register-accumulates, flushes one atomic per graph boundary.
#define POOL_WAVES 512
#define POOL_PER   ((N_NODES + POOL_WAVES - 1) / POOL_WAVES)
__global__ void k_pool(const float* __restrict__ H2, const int* __restrict__ batch,
                       float* __restrict__ gsum, int* __restrict__ gcnt) {
    int wid  = (blockIdx.x * blockDim.x + threadIdx.x) >> 6;
    int lane = threadIdx.x & 63;
    int n0 = wid * POOL_PER;
    if (n0 >= N_NODES) return;
    int n1 = min(n0 + POOL_PER, N_NODES);
    int g = batch[n0];
    float acc = 0.0f;
    int c = 0;
    for (int n = n0; n < n1; n++) {
        int gn = batch[n];
        if (gn != g) {
            atomicAdd(&gsum[g * HIDDEN + lane], acc);
            if (lane == 0) atomicAdd(&gcnt[g], c);
            acc = 0.0f; c = 0; g = gn;
        }
        acc += H2[(size_t)n * HIDDEN + lane];
        c++;
    }
    atomicAdd(&gsum[g * HIDDEN + lane], acc);
    if (lane == 0) atomicAdd(&gcnt[g], c);
}

// 9) out[g,c] = (gsum[g,:] @ Wl[:,c]) / max(cnt,1) + bl[c]
__global__ void k_final(const float* __restrict__ gsum, const int* __restrict__ gcnt,
                        const float* __restrict__ Wl, const float* __restrict__ bl,
                        float* __restrict__ out) {
    int t = blockIdx.x * blockDim.x + threadIdx.x;   // g*5 + c
    if (t >= N_GRAPHS * N_CLASSES) return;
    int g = t / N_CLASSES, c = t % N_CLASSES;
    float cntf = fmaxf((float)gcnt[g], 1.0f);
    float acc = 0.0f;
#pragma unroll
    for (int k = 0; k < HIDDEN; k++) acc = fmaf(gsum[g * HIDDEN + k], Wl[k * N_CLASSES + c], acc);
    out[t] = acc / cntf + bl[c];
}

// ---------------------------------------------------------------------------
extern "C" void kernel_launch(void* const* d_in, const int* in_sizes, int n_in,
                              void* d_out, int out_size, void* d_ws, size_t ws_size,
                              hipStream_t stream) {
    const float* x     = (const float*)d_in[0];
    const int*   ei    = (const int*)  d_in[1];   // [2, N_EDGES] flat: src then dst
    const int*   batch = (const int*)  d_in[2];
    const float* W1    = (const float*)d_in[3];
    const float* b1    = (const float*)d_in[4];
    const float* W2    = (const float*)d_in[5];
    const float* b2    = (const float*)d_in[6];
    const float* Wl    = (const float*)d_in[7];
    const float* bl    = (const float*)d_in[8];
    float* out = (float*)d_out;

    const int* src = ei;
    const int* dst = ei + N_EDGES;

    // workspace layout
    int*   cnt    = (int*)d_ws;                          // N
    float* dis    = (float*)(cnt + N_NODES);             // N
    int*   rowptr = (int*)(dis + N_NODES);               // N
    int*   cursor = rowptr + N_NODES;                    // N
    int*   bsum   = cursor + N_NODES;                    // 512 (scan block sums)
    int*   elist  = bsum + 512;                          // E
    float* A      = (float*)(elist + N_EDGES);           // N*64
    float* B      = A + (size_t)N_NODES * HIDDEN;        // N*64
    float* gsum   = B + (size_t)N_NODES * HIDDEN;        // 512*64
    int*   gcnt   = (int*)(gsum + N_GRAPHS * HIDDEN);    // 512

    const int BS = 256;
    const int g_edges = (N_EDGES + BS - 1) / BS;
    const int g_nodes = (N_NODES + BS - 1) / BS;
    const int g_nh    = (N_NODES * HIDDEN + BS - 1) / BS;
    const int g_gather = (N_NODES + 3) / 4;              // 4 nodes (waves) per block

    // degree + norm
    hipMemsetAsync(cnt, 0, N_NODES * sizeof(int), stream);
    k_deg<<<g_edges, BS, 0, stream>>>(dst, cnt);
    k_dis<<<g_nodes, BS, 0, stream>>>(cnt, dis);

    // CSR build: scan + fill
    k_scan_local<<<NBLK256, 256, 0, stream>>>(cnt, rowptr, bsum);
    k_scan_bsum<<<1, 512, 0, stream>>>(bsum);
    k_scan_add<<<NBLK256, 256, 0, stream>>>(rowptr, bsum, cursor);
    k_fill<<<g_edges, BS, 0, stream>>>(src, dst, cursor, elist);

    // layer 1: A = xW1 ; B = relu(gather(A) + self + b1)
    k_xw1<<<g_nh, BS, 0, stream>>>(x, W1, A);
    k_gather<true><<<g_gather, BS, 0, stream>>>(rowptr, cnt, elist, dis, A, b1, B);

    // layer 2: A = B@W2 ; B = gather(A) + self + b2
    k_hw2<<<g_nh, BS, 0, stream>>>(B, W2, A);
    k_gather<false><<<g_gather, BS, 0, stream>>>(rowptr, cnt, elist, dis, A, b2, B);

    // pooling + head
    hipMemsetAsync(gsum, 0, N_GRAPHS * HIDDEN * sizeof(float), stream);
    hipMemsetAsync(gcnt, 0, N_GRAPHS * sizeof(int), stream);
    k_pool<<<(POOL_WAVES * 64 + BS - 1) / BS, BS, 0, stream>>>(B, batch, gsum, gcnt);
    k_final<<<(N_GRAPHS * N_CLASSES + BS - 1) / BS, BS, 0, stream>>>(gsum, gcnt, Wl, bl, out);
}

// Round 3
// 399.677 us; speedup vs baseline: 6.4296x; 1.3294x over previous
//
#include <hip/hip_runtime.h>
#include <hip/hip_bf16.h>

#define N_NODES   100000
#define N_EDGES   1250000
#define N_GRAPHS  512
#define HIDDEN    64
#define F_IN      3
#define N_CLASSES 5

#define NBLK256   ((N_NODES + 255) / 256)   // 391 scan blocks

// ---------------------------------------------------------------------------
// 1) degree histogram on dst (self-loop added later as +1)
__global__ void k_deg(const int* __restrict__ dst, int* __restrict__ cnt) {
    int i = blockIdx.x * blockDim.x + threadIdx.x;
    if (i < N_EDGES) atomicAdd(&cnt[dst[i]], 1);
}

// 2) dis[i] = 1/sqrt(deg+1)
__global__ void k_dis(const int* __restrict__ cnt, float* __restrict__ dis) {
    int i = blockIdx.x * blockDim.x + threadIdx.x;
    if (i < N_NODES) dis[i] = rsqrtf((float)cnt[i] + 1.0f);
}

// 3) xs[n,c] = x[n,c] * dis[n]   (pre-scaled source features)
__global__ void k_xs(const float* __restrict__ x, const float* __restrict__ dis,
                     float* __restrict__ xs) {
    int t = blockIdx.x * blockDim.x + threadIdx.x;
    if (t >= N_NODES * F_IN) return;
    xs[t] = x[t] * dis[t / F_IN];
}

// --- 3-kernel exclusive scan of cnt -> rowptr --------------------------------
__global__ void k_scan_local(const int* __restrict__ cnt, int* __restrict__ rp,
                             int* __restrict__ bsum) {
    __shared__ int s[256];
    int i = blockIdx.x * 256 + threadIdx.x;
    int v = (i < N_NODES) ? cnt[i] : 0;
    s[threadIdx.x] = v;
    __syncthreads();
    for (int off = 1; off < 256; off <<= 1) {
        int t = (threadIdx.x >= off) ? s[threadIdx.x - off] : 0;
        __syncthreads();
        s[threadIdx.x] += t;
        __syncthreads();
    }
    if (i < N_NODES) rp[i] = s[threadIdx.x] - v;           // exclusive
    if (threadIdx.x == 255) bsum[blockIdx.x] = s[255];     // block total
}

__global__ void k_scan_bsum(int* __restrict__ bsum) {      // 1 block, 512 thr
    __shared__ int s[512];
    int v = (threadIdx.x < NBLK256) ? bsum[threadIdx.x] : 0;
    s[threadIdx.x] = v;
    __syncthreads();
    for (int off = 1; off < 512; off <<= 1) {
        int t = (threadIdx.x >= off) ? s[threadIdx.x - off] : 0;
        __syncthreads();
        s[threadIdx.x] += t;
        __syncthreads();
    }
    if (threadIdx.x < NBLK256) bsum[threadIdx.x] = s[threadIdx.x] - v; // exclusive
}

__global__ void k_scan_add(int* __restrict__ rp, const int* __restrict__ bsum,
                           int* __restrict__ cursor) {
    int i = blockIdx.x * 256 + threadIdx.x;
    if (i < N_NODES) {
        int v = rp[i] + bsum[blockIdx.x];
        rp[i] = v;
        cursor[i] = v;
    }
}

// 4) scatter edges into CSR: elist[pos] = src, grouped by dst
__global__ void k_fill(const int* __restrict__ src, const int* __restrict__ dst,
                       int* __restrict__ cursor, int* __restrict__ elist) {
    int e = blockIdx.x * blockDim.x + threadIdx.x;
    if (e < N_EDGES) {
        int pos = atomicAdd(&cursor[dst[e]], 1);
        elist[pos] = src[e];
    }
}

// 5) 3-channel gather (layer-1 aggregation in input space):
//    aggx[n] = dis[n] * ( sum_{s in N(n)} xs[s] + xs[n] )      (xs = x*dis)
//    one thread per node, serial edge loop (all data L2-resident).
__global__ void k_aggx(const int* __restrict__ rp, const int* __restrict__ cnt,
                       const int* __restrict__ elist, const float* __restrict__ dis,
                       const float* __restrict__ xs, float* __restrict__ aggx) {
    int n = blockIdx.x * blockDim.x + threadIdx.x;
    if (n >= N_NODES) return;
    int start = rp[n], deg = cnt[n];
    float a0 = 0.f, a1 = 0.f, a2 = 0.f;
    for (int e = start; e < start + deg; e++) {
        int s = elist[e];
        a0 += xs[s * 3 + 0];
        a1 += xs[s * 3 + 1];
        a2 += xs[s * 3 + 2];
    }
    float dn = dis[n];
    aggx[n * 3 + 0] = dn * (a0 + xs[n * 3 + 0]);
    aggx[n * 3 + 1] = dn * (a1 + xs[n * 3 + 1]);
    aggx[n * 3 + 2] = dn * (a2 + xs[n * 3 + 2]);
}

// 6) h1s[n,h] = relu( aggx[n,:] @ W1[:,h] + b1[h] ) * dis[n]   (pre-scaled h1)
__global__ void k_l1(const float* __restrict__ aggx, const float* __restrict__ W1,
                     const float* __restrict__ b1, const float* __restrict__ dis,
                     float* __restrict__ h1s) {
    int t = blockIdx.x * blockDim.x + threadIdx.x;   // n*64 + h
    if (t >= N_NODES * HIDDEN) return;
    int n = t >> 6, h = t & 63;
    float a0 = aggx[n * 3 + 0], a1 = aggx[n * 3 + 1], a2 = aggx[n * 3 + 2];
    float v = a0 * W1[h] + a1 * W1[HIDDEN + h] + a2 * W1[2 * HIDDEN + h] + b1[h];
    h1s[t] = fmaxf(v, 0.0f) * dis[n];
}

// 7) 64-channel gather (layer 2): B[n] = dis[n] * ( sum_s h1s[s] + h1s[n] )
//    wave per node; lane = (edge-group eg 0..3, channel-quad ch4 0..15);
//    4 edges per wave-step via float4 row reads, butterfly-reduce at end.
__global__ void k_gather64(const int* __restrict__ rp, const int* __restrict__ cnt,
                           const int* __restrict__ elist,
                           const float* __restrict__ dis,
                           const float* __restrict__ H, float* __restrict__ OUT) {
    int node = blockIdx.x * 4 + (threadIdx.x >> 6);
    int lane = threadIdx.x & 63;
    if (node >= N_NODES) return;
    int start = rp[node], deg = cnt[node];
    int eg  = lane >> 4;     // which of 4 concurrent edges
    int ch4 = lane & 15;     // which float4 of the row
    float4 acc = make_float4(0.f, 0.f, 0.f, 0.f);
    for (int base = 0; base < deg; base += 64) {
        int m = min(64, deg - base);
        int eid = (lane < m) ? elist[start + base + lane] : 0;
        int k = 0;
        for (; k + 4 <= m; k += 4) {
            int s = __shfl(eid, k + eg);
            float4 v = *(const float4*)(H + (size_t)s * HIDDEN + ch4 * 4);
            acc.x += v.x; acc.y += v.y; acc.z += v.z; acc.w += v.w;
        }
        for (; k < m; k++) {                       // <=3 leftover edges
            int s = __shfl(eid, k);
            if (eg == 0) {
                float4 v = *(const float4*)(H + (size_t)s * HIDDEN + ch4 * 4);
                acc.x += v.x; acc.y += v.y; acc.z += v.z; acc.w += v.w;
            }
        }
    }
    // reduce the 4 edge-groups (lanes l, l^16, l^32, l^48)
    acc.x += __shfl_xor(acc.x, 16); acc.y += __shfl_xor(acc.y, 16);
    acc.z += __shfl_xor(acc.z, 16); acc.w += __shfl_xor(acc.w, 16);
    acc.x += __shfl_xor(acc.x, 32); acc.y += __shfl_xor(acc.y, 32);
    acc.z += __shfl_xor(acc.z, 32); acc.w += __shfl_xor(acc.w, 32);
    if (lane < 16) {
        float dn = dis[node];
        float4 self = *(const float4*)(H + (size_t)node * HIDDEN + lane * 4);
        float4 o;
        o.x = dn * (acc.x + self.x);
        o.y = dn * (acc.y + self.y);
        o.z = dn * (acc.z + self.z);
        o.w = dn * (acc.w + self.w);
        *(float4*)(OUT + (size_t)node * HIDDEN + lane * 4) = o;
    }
}

// 8) pooling: batch is SORTED -> wave walks contiguous node range,
//    register-accumulates, flushes one atomic per graph boundary.
#define POOL_WAVES 512
#define POOL_PER   ((N_NODES + POOL_WAVES - 1) / POOL_WAVES)
__global__ void k_pool(const float* __restrict__ H2, const int* __restrict__ batch,
                       float* __restrict__ gsum, int* __restrict__ gcnt) {
    int wid  = (blockIdx.x * blockDim.x + threadIdx.x) >> 6;
    int lane = threadIdx.x & 63;
    int n0 = wid * POOL_PER;
    if (n0 >= N_NODES) return;
    int n1 = min(n0 + POOL_PER, N_NODES);
    int g = batch[n0];
    float acc = 0.0f;
    int c = 0;
    for (int n = n0; n < n1; n++) {
        int gn = batch[n];
        if (gn != g) {
            atomicAdd(&gsum[g * HIDDEN + lane], acc);
            if (lane == 0) atomicAdd(&gcnt[g], c);
            acc = 0.0f; c = 0; g = gn;
        }
        acc += H2[(size_t)n * HIDDEN + lane];
        c++;
    }
    atomicAdd(&gsum[g * HIDDEN + lane], acc);
    if (lane == 0) atomicAdd(&gcnt[g], c);
}

// 9) fold head: Wc = W2 @ Wl  [64,5],  bc = b2 @ Wl + bl  [5]
__global__ void k_wc(const float* __restrict__ W2, const float* __restrict__ Wl,
                     const float* __restrict__ b2, const float* __restrict__ bl,
                     float* __restrict__ Wc, float* __restrict__ bc) {
    int t = threadIdx.x;
    if (t < HIDDEN * N_CLASSES) {
        int k = t / N_CLASSES, c = t % N_CLASSES;
        float acc = 0.0f;
#pragma unroll
        for (int j = 0; j < HIDDEN; j++)
            acc = fmaf(W2[k * HIDDEN + j], Wl[j * N_CLASSES + c], acc);
        Wc[t] = acc;
    } else if (t < HIDDEN * N_CLASSES + N_CLASSES) {
        int c = t - HIDDEN * N_CLASSES;
        float acc = bl[c];
#pragma unroll
        for (int j = 0; j < HIDDEN; j++)
            acc = fmaf(b2[j], Wl[j * N_CLASSES + c], acc);
        bc[c] = acc;
    }
}

// 10) out[g,c] = (gsum[g,:] @ Wc[:,c]) / max(cnt,1) + bc[c]
__global__ void k_head(const float* __restrict__ gsum, const int* __restrict__ gcnt,
                       const float* __restrict__ Wc, const float* __restrict__ bc,
                       float* __restrict__ out) {
    int t = blockIdx.x * blockDim.x + threadIdx.x;   // g*5 + c
    if (t >= N_GRAPHS * N_CLASSES) return;
    int g = t / N_CLASSES, c = t % N_CLASSES;
    float cntf = fmaxf((float)gcnt[g], 1.0f);
    float acc = 0.0f;
#pragma unroll
    for (int k = 0; k < HIDDEN; k++)
        acc = fmaf(gsum[g * HIDDEN + k], Wc[k * N_CLASSES + c], acc);
    out[t] = acc / cntf + bc[c];
}

// ---------------------------------------------------------------------------
extern "C" void kernel_launch(void* const* d_in, const int* in_sizes, int n_in,
                              void* d_out, int out_size, void* d_ws, size_t ws_size,
                              hipStream_t stream) {
    const float* x     = (const float*)d_in[0];
    const int*   ei    = (const int*)  d_in[1];   // [2, N_EDGES] flat: src then dst
    const int*   batch = (const int*)  d_in[2];
    const float* W1    = (const float*)d_in[3];
    const float* b1    = (const float*)d_in[4];
    const float* W2    = (const float*)d_in[5];
    const float* b2    = (const float*)d_in[6];
    const float* Wl    = (const float*)d_in[7];
    const float* bl    = (const float*)d_in[8];
    float* out = (float*)d_out;

    const int* src = ei;
    const int* dst = ei + N_EDGES;

    // workspace layout (4B units)
    int*   cnt    = (int*)d_ws;                          // N
    float* dis    = (float*)(cnt + N_NODES);             // N
    int*   rowptr = (int*)(dis + N_NODES);               // N
    int*   cursor = rowptr + N_NODES;                    // N
    int*   bsum   = cursor + N_NODES;                    // 512
    int*   elist  = bsum + 512;                          // E
    float* xs     = (float*)(elist + N_EDGES);           // N*3
    float* aggx   = xs + (size_t)N_NODES * F_IN;         // N*3
    float* h1s    = aggx + (size_t)N_NODES * F_IN;       // N*64
    float* B      = h1s + (size_t)N_NODES * HIDDEN;      // N*64  (agg2)
    float* gsum   = B + (size_t)N_NODES * HIDDEN;        // 512*64
    int*   gcnt   = (int*)(gsum + N_GRAPHS * HIDDEN);    // 512
    float* Wc     = (float*)(gcnt + N_GRAPHS);           // 64*5
    float* bc     = Wc + HIDDEN * N_CLASSES;             // 5

    const int BS = 256;
    const int g_edges  = (N_EDGES + BS - 1) / BS;
    const int g_nodes  = (N_NODES + BS - 1) / BS;
    const int g_nh     = (N_NODES * HIDDEN + BS - 1) / BS;
    const int g_n3     = (N_NODES * F_IN + BS - 1) / BS;
    const int g_gather = (N_NODES + 3) / 4;

    // degree + norm + pre-scaled x
    hipMemsetAsync(cnt, 0, N_NODES * sizeof(int), stream);
    k_deg<<<g_edges, BS, 0, stream>>>(dst, cnt);
    k_dis<<<g_nodes, BS, 0, stream>>>(cnt, dis);
    k_xs<<<g_n3, BS, 0, stream>>>(x, dis, xs);

    // CSR build: scan + fill
    k_scan_local<<<NBLK256, 256, 0, stream>>>(cnt, rowptr, bsum);
    k_scan_bsum<<<1, 512, 0, stream>>>(bsum);
    k_scan_add<<<NBLK256, 256, 0, stream>>>(rowptr, bsum, cursor);
    k_fill<<<g_edges, BS, 0, stream>>>(src, dst, cursor, elist);

    // head fold (independent, tiny)
    k_wc<<<1, 384, 0, stream>>>(W2, Wl, b2, bl, Wc, bc);

    // layer 1 in input space: aggx = norm-gather(xs); h1s = relu(aggx@W1+b1)*dis
    k_aggx<<<g_nodes, BS, 0, stream>>>(rowptr, cnt, elist, dis, xs, aggx);
    k_l1<<<g_nh, BS, 0, stream>>>(aggx, W1, b1, dis, h1s);

    // layer 2 aggregation only (W2 folded into head): B = norm-gather(h1s)
    k_gather64<<<g_gather, BS, 0, stream>>>(rowptr, cnt, elist, dis, h1s, B);

    // pooling + folded head
    hipMemsetAsync(gsum, 0, N_GRAPHS * HIDDEN * sizeof(float), stream);
    hipMemsetAsync(gcnt, 0, N_GRAPHS * sizeof(int), stream);
    k_pool<<<(POOL_WAVES * 64 + BS - 1) / BS, BS, 0, stream>>>(B, batch, gsum, gcnt);
    k_head<<<(N_GRAPHS * N_CLASSES + BS - 1) / BS, BS, 0, stream>>>(gsum, gcnt, Wc, bc, out);
}

// Round 4
// 302.383 us; speedup vs baseline: 8.4983x; 1.3218x over previous
//
#include <hip/hip_runtime.h>
#include <hip/hip_bf16.h>

#define N_NODES   100000
#define N_EDGES   1250000
#define N_GRAPHS  512
#define HIDDEN    64
#define F_IN      3
#define N_CLASSES 5

// bucket sort parameters
#define BKT_SHIFT 9
#define BKT_NODES 512                                    // nodes per bucket
#define N_BKT     ((N_NODES + BKT_NODES - 1) / BKT_NODES)  // 196
#define EBLK      256                                    // edge blocks in P1/P3
#define ECHUNK    ((N_EDGES + EBLK - 1) / EBLK)          // 4883

// ---------------------------------------------------------------------------
// P1: per-edge-block histogram over dst buckets (LDS, no global atomics)
__global__ void k_hist(const int* __restrict__ dst, int* __restrict__ hist) {
    __shared__ int h[N_BKT];
    for (int i = threadIdx.x; i < N_BKT; i += 256) h[i] = 0;
    __syncthreads();
    int e0 = blockIdx.x * ECHUNK, e1 = min(e0 + ECHUNK, N_EDGES);
    for (int e = e0 + threadIdx.x; e < e1; e += 256)
        atomicAdd(&h[dst[e] >> BKT_SHIFT], 1);
    __syncthreads();
    for (int i = threadIdx.x; i < N_BKT; i += 256)
        hist[blockIdx.x * N_BKT + i] = h[i];
}

// P2a: column scan — colscan[B][b] = sum_{B'<B} hist[B'][b]; btot[b] = total
__global__ void k_colscan(const int* __restrict__ hist, int* __restrict__ colscan,
                          int* __restrict__ btot) {
    __shared__ int s[256];
    int b = blockIdx.x;
    int v = hist[threadIdx.x * N_BKT + b];
    s[threadIdx.x] = v;
    __syncthreads();
    for (int off = 1; off < 256; off <<= 1) {
        int t = (threadIdx.x >= off) ? s[threadIdx.x - off] : 0;
        __syncthreads();
        s[threadIdx.x] += t;
        __syncthreads();
    }
    colscan[threadIdx.x * N_BKT + b] = s[threadIdx.x] - v;
    if (threadIdx.x == 255) btot[b] = s[255];
}

// P2b: exclusive scan of bucket totals -> base[0..N_BKT]
__global__ void k_bktbase(const int* __restrict__ btot, int* __restrict__ base) {
    __shared__ int s[256];
    int v = (threadIdx.x < N_BKT) ? btot[threadIdx.x] : 0;
    s[threadIdx.x] = v;
    __syncthreads();
    for (int off = 1; off < 256; off <<= 1) {
        int t = (threadIdx.x >= off) ? s[threadIdx.x - off] : 0;
        __syncthreads();
        s[threadIdx.x] += t;
        __syncthreads();
    }
    if (threadIdx.x < N_BKT) base[threadIdx.x] = s[threadIdx.x] - v;
    if (threadIdx.x == N_BKT - 1) base[N_BKT] = s[threadIdx.x];
}

// P3: scatter edges into bucket-grouped ebuf via LDS cursors
__global__ void k_bktscatter(const int* __restrict__ src, const int* __restrict__ dst,
                             const int* __restrict__ base, const int* __restrict__ colscan,
                             int2* __restrict__ ebuf) {
    __shared__ int cur[N_BKT];
    for (int i = threadIdx.x; i < N_BKT; i += 256)
        cur[i] = base[i] + colscan[blockIdx.x * N_BKT + i];
    __syncthreads();
    int e0 = blockIdx.x * ECHUNK, e1 = min(e0 + ECHUNK, N_EDGES);
    for (int e = e0 + threadIdx.x; e < e1; e += 256) {
        int s = src[e], d = dst[e];
        int pos = atomicAdd(&cur[d >> BKT_SHIFT], 1);
        ebuf[pos] = make_int2(s, d);
    }
}

// P4: per-bucket node fill: degree hist (LDS) -> rowptr + dis (coalesced),
//     then LDS-cursor scatter of src into elist (contiguous region per block).
__global__ void k_bktfill(const int2* __restrict__ ebuf, const int* __restrict__ base,
                          int* __restrict__ rowptr, float* __restrict__ dis,
                          int* __restrict__ elist) {
    __shared__ int cnt_l[BKT_NODES];
    __shared__ int rp_l[BKT_NODES];
    __shared__ int ps[256];
    int b = blockIdx.x, tid = threadIdx.x;
    int n0 = b * BKT_NODES;
    int e0 = base[b], e1 = base[b + 1];
    cnt_l[tid] = 0; cnt_l[tid + 256] = 0;
    __syncthreads();
    for (int e = e0 + tid; e < e1; e += 256)
        atomicAdd(&cnt_l[ebuf[e].y & (BKT_NODES - 1)], 1);
    __syncthreads();
    int a = cnt_l[2 * tid], c = cnt_l[2 * tid + 1];
    int p = a + c;
    ps[tid] = p;
    __syncthreads();
    for (int off = 1; off < 256; off <<= 1) {
        int t = (tid >= off) ? ps[tid - off] : 0;
        __syncthreads();
        ps[tid] += t;
        __syncthreads();
    }
    int bs = ps[tid] - p;                 // exclusive over pairs
    rp_l[2 * tid] = bs;
    rp_l[2 * tid + 1] = bs + a;
    __syncthreads();
#pragma unroll
    for (int k = 0; k < 2; k++) {
        int i = tid + k * 256;
        int node = n0 + i;
        if (node < N_NODES) {
            rowptr[node] = e0 + rp_l[i];
            dis[node] = rsqrtf((float)cnt_l[i] + 1.0f);
        }
    }
    if (b == 0 && tid == 0) rowptr[N_NODES] = N_EDGES;
    __syncthreads();
    cnt_l[tid] = rp_l[tid];               // reuse cnt_l as cursor
    cnt_l[tid + 256] = rp_l[tid + 256];
    __syncthreads();
    for (int e = e0 + tid; e < e1; e += 256) {
        int2 sd = ebuf[e];
        int pos = atomicAdd(&cnt_l[sd.y & (BKT_NODES - 1)], 1);
        elist[e0 + pos] = sd.x;
    }
}

// ---------------------------------------------------------------------------
// xs[n,c] = x[n,c] * dis[n]
__global__ void k_xs(const float* __restrict__ x, const float* __restrict__ dis,
                     float* __restrict__ xs) {
    int t = blockIdx.x * blockDim.x + threadIdx.x;
    if (t >= N_NODES * F_IN) return;
    xs[t] = x[t] * dis[t / F_IN];
}

// 3-channel gather: aggx[n] = dis[n] * ( sum_{s in N(n)} xs[s] + xs[n] )
__global__ void k_aggx(const int* __restrict__ rp, const int* __restrict__ elist,
                       const float* __restrict__ dis, const float* __restrict__ xs,
                       float* __restrict__ aggx) {
    int n = blockIdx.x * blockDim.x + threadIdx.x;
    if (n >= N_NODES) return;
    int start = rp[n], end = rp[n + 1];
    float a0 = 0.f, a1 = 0.f, a2 = 0.f;
    for (int e = start; e < end; e++) {
        int s = elist[e];
        a0 += xs[s * 3 + 0];
        a1 += xs[s * 3 + 1];
        a2 += xs[s * 3 + 2];
    }
    float dn = dis[n];
    aggx[n * 3 + 0] = dn * (a0 + xs[n * 3 + 0]);
    aggx[n * 3 + 1] = dn * (a1 + xs[n * 3 + 1]);
    aggx[n * 3 + 2] = dn * (a2 + xs[n * 3 + 2]);
}

// h1s[n,h] = relu( aggx[n,:] @ W1[:,h] + b1[h] ) * dis[n]
__global__ void k_l1(const float* __restrict__ aggx, const float* __restrict__ W1,
                     const float* __restrict__ b1, const float* __restrict__ dis,
                     float* __restrict__ h1s) {
    int t = blockIdx.x * blockDim.x + threadIdx.x;   // n*64 + h
    if (t >= N_NODES * HIDDEN) return;
    int n = t >> 6, h = t & 63;
    float a0 = aggx[n * 3 + 0], a1 = aggx[n * 3 + 1], a2 = aggx[n * 3 + 2];
    float v = a0 * W1[h] + a1 * W1[HIDDEN + h] + a2 * W1[2 * HIDDEN + h] + b1[h];
    h1s[t] = fmaxf(v, 0.0f) * dis[n];
}

// 64-channel gather: B[n] = dis[n] * ( sum_s h1s[s] + h1s[n] )
__global__ void k_gather64(const int* __restrict__ rp, const int* __restrict__ elist,
                           const float* __restrict__ dis,
                           const float* __restrict__ H, float* __restrict__ OUT) {
    int node = blockIdx.x * 4 + (threadIdx.x >> 6);
    int lane = threadIdx.x & 63;
    if (node >= N_NODES) return;
    int start = rp[node], deg = rp[node + 1] - start;
    int eg  = lane >> 4;     // which of 4 concurrent edges
    int ch4 = lane & 15;     // which float4 of the row
    float4 acc = make_float4(0.f, 0.f, 0.f, 0.f);
    for (int base = 0; base < deg; base += 64) {
        int m = min(64, deg - base);
        int eid = (lane < m) ? elist[start + base + lane] : 0;
        int k = 0;
        for (; k + 4 <= m; k += 4) {
            int s = __shfl(eid, k + eg);
            float4 v = *(const float4*)(H + (size_t)s * HIDDEN + ch4 * 4);
            acc.x += v.x; acc.y += v.y; acc.z += v.z; acc.w += v.w;
        }
        for (; k < m; k++) {
            int s = __shfl(eid, k);
            if (eg == 0) {
                float4 v = *(const float4*)(H + (size_t)s * HIDDEN + ch4 * 4);
                acc.x += v.x; acc.y += v.y; acc.z += v.z; acc.w += v.w;
            }
        }
    }
    acc.x += __shfl_xor(acc.x, 16); acc.y += __shfl_xor(acc.y, 16);
    acc.z += __shfl_xor(acc.z, 16); acc.w += __shfl_xor(acc.w, 16);
    acc.x += __shfl_xor(acc.x, 32); acc.y += __shfl_xor(acc.y, 32);
    acc.z += __shfl_xor(acc.z, 32); acc.w += __shfl_xor(acc.w, 32);
    if (lane < 16) {
        float dn = dis[node];
        float4 self = *(const float4*)(H + (size_t)node * HIDDEN + lane * 4);
        float4 o;
        o.x = dn * (acc.x + self.x);
        o.y = dn * (acc.y + self.y);
        o.z = dn * (acc.z + self.z);
        o.w = dn * (acc.w + self.w);
        *(float4*)(OUT + (size_t)node * HIDDEN + lane * 4) = o;
    }
}

// pooling over sorted batch ids
#define POOL_WAVES 512
#define POOL_PER   ((N_NODES + POOL_WAVES - 1) / POOL_WAVES)
__global__ void k_pool(const float* __restrict__ H2, const int* __restrict__ batch,
                       float* __restrict__ gsum, int* __restrict__ gcnt) {
    int wid  = (blockIdx.x * blockDim.x + threadIdx.x) >> 6;
    int lane = threadIdx.x & 63;
    int n0 = wid * POOL_PER;
    if (n0 >= N_NODES) return;
    int n1 = min(n0 + POOL_PER, N_NODES);
    int g = batch[n0];
    float acc = 0.0f;
    int c = 0;
    for (int n = n0; n < n1; n++) {
        int gn = batch[n];
        if (gn != g) {
            atomicAdd(&gsum[g * HIDDEN + lane], acc);
            if (lane == 0) atomicAdd(&gcnt[g], c);
            acc = 0.0f; c = 0; g = gn;
        }
        acc += H2[(size_t)n * HIDDEN + lane];
        c++;
    }
    atomicAdd(&gsum[g * HIDDEN + lane], acc);
    if (lane == 0) atomicAdd(&gcnt[g], c);
}

// fold head: Wc = W2 @ Wl  [64,5],  bc = b2 @ Wl + bl  [5]
__global__ void k_wc(const float* __restrict__ W2, const float* __restrict__ Wl,
                     const float* __restrict__ b2, const float* __restrict__ bl,
                     float* __restrict__ Wc, float* __restrict__ bc) {
    int t = threadIdx.x;
    if (t < HIDDEN * N_CLASSES) {
        int k = t / N_CLASSES, c = t % N_CLASSES;
        float acc = 0.0f;
#pragma unroll
        for (int j = 0; j < HIDDEN; j++)
            acc = fmaf(W2[k * HIDDEN + j], Wl[j * N_CLASSES + c], acc);
        Wc[t] = acc;
    } else if (t < HIDDEN * N_CLASSES + N_CLASSES) {
        int c = t - HIDDEN * N_CLASSES;
        float acc = bl[c];
#pragma unroll
        for (int j = 0; j < HIDDEN; j++)
            acc = fmaf(b2[j], Wl[j * N_CLASSES + c], acc);
        bc[c] = acc;
    }
}

// out[g,c] = (gsum[g,:] @ Wc[:,c]) / max(cnt,1) + bc[c]
__global__ void k_head(const float* __restrict__ gsum, const int* __restrict__ gcnt,
                       const float* __restrict__ Wc, const float* __restrict__ bc,
                       float* __restrict__ out) {
    int t = blockIdx.x * blockDim.x + threadIdx.x;   // g*5 + c
    if (t >= N_GRAPHS * N_CLASSES) return;
    int g = t / N_CLASSES, c = t % N_CLASSES;
    float cntf = fmaxf((float)gcnt[g], 1.0f);
    float acc = 0.0f;
#pragma unroll
    for (int k = 0; k < HIDDEN; k++)
        acc = fmaf(gsum[g * HIDDEN + k], Wc[k * N_CLASSES + c], acc);
    out[t] = acc / cntf + bc[c];
}

// ---------------------------------------------------------------------------
extern "C" void kernel_launch(void* const* d_in, const int* in_sizes, int n_in,
                              void* d_out, int out_size, void* d_ws, size_t ws_size,
                              hipStream_t stream) {
    const float* x     = (const float*)d_in[0];
    const int*   ei    = (const int*)  d_in[1];   // [2, N_EDGES] flat: src then dst
    const int*   batch = (const int*)  d_in[2];
    const float* W1    = (const float*)d_in[3];
    const float* b1    = (const float*)d_in[4];
    const float* W2    = (const float*)d_in[5];
    const float* b2    = (const float*)d_in[6];
    const float* Wl    = (const float*)d_in[7];
    const float* bl    = (const float*)d_in[8];
    float* out = (float*)d_out;

    const int* src = ei;
    const int* dst = ei + N_EDGES;

    // workspace layout (4B units; ebuf first for 8B alignment)
    int2*  ebuf    = (int2*)d_ws;                        // E int2
    int*   elist   = (int*)(ebuf + N_EDGES);             // E
    int*   hist    = elist + N_EDGES;                    // EBLK*N_BKT
    int*   colscan = hist + EBLK * N_BKT;                // EBLK*N_BKT
    int*   btot    = colscan + EBLK * N_BKT;             // N_BKT
    int*   base    = btot + N_BKT;                       // N_BKT+1
    int*   rowptr  = base + N_BKT + 1;                   // N+1
    float* dis     = (float*)(rowptr + N_NODES + 1);     // N
    float* xs      = dis + N_NODES;                      // N*3
    float* aggx    = xs + (size_t)N_NODES * F_IN;        // N*3
    float* h1s     = aggx + (size_t)N_NODES * F_IN;      // N*64
    float* B       = h1s + (size_t)N_NODES * HIDDEN;     // N*64
    float* gsum    = B + (size_t)N_NODES * HIDDEN;       // 512*64
    int*   gcnt    = (int*)(gsum + N_GRAPHS * HIDDEN);   // 512
    float* Wc      = (float*)(gcnt + N_GRAPHS);          // 64*5
    float* bc      = Wc + HIDDEN * N_CLASSES;            // 5

    const int BS = 256;
    const int g_nodes  = (N_NODES + BS - 1) / BS;
    const int g_nh     = (N_NODES * HIDDEN + BS - 1) / BS;
    const int g_n3     = (N_NODES * F_IN + BS - 1) / BS;
    const int g_gather = (N_NODES + 3) / 4;

    // CSR build: two-level counting sort, no global atomics
    k_hist<<<EBLK, 256, 0, stream>>>(dst, hist);
    k_colscan<<<N_BKT, 256, 0, stream>>>(hist, colscan, btot);
    k_bktbase<<<1, 256, 0, stream>>>(btot, base);
    k_bktscatter<<<EBLK, 256, 0, stream>>>(src, dst, base, colscan, ebuf);
    k_bktfill<<<N_BKT, 256, 0, stream>>>(ebuf, base, rowptr, dis, elist);

    // head fold (independent, tiny)
    k_wc<<<1, 384, 0, stream>>>(W2, Wl, b2, bl, Wc, bc);

    // layer 1 in input space
    k_xs<<<g_n3, BS, 0, stream>>>(x, dis, xs);
    k_aggx<<<g_nodes, BS, 0, stream>>>(rowptr, elist, dis, xs, aggx);
    k_l1<<<g_nh, BS, 0, stream>>>(aggx, W1, b1, dis, h1s);

    // layer 2 aggregation (W2 folded into head)
    k_gather64<<<g_gather, BS, 0, stream>>>(rowptr, elist, dis, h1s, B);

    // pooling + folded head
    hipMemsetAsync(gsum, 0, N_GRAPHS * HIDDEN * sizeof(float), stream);
    hipMemsetAsync(gcnt, 0, N_GRAPHS * sizeof(int), stream);
    k_pool<<<(POOL_WAVES * 64 + BS - 1) / BS, BS, 0, stream>>>(B, batch, gsum, gcnt);
    k_head<<<(N_GRAPHS * N_CLASSES + BS - 1) / BS, BS, 0, stream>>>(gsum, gcnt, Wc, bc, out);
}

// Round 5
// 235.147 us; speedup vs baseline: 10.9283x; 1.2859x over previous
//
#include <hip/hip_runtime.h>
#include <hip/hip_bf16.h>

#define N_NODES   100000
#define N_EDGES   1250000
#define N_GRAPHS  512
#define HIDDEN    64
#define F_IN      3
#define N_CLASSES 5

// bucket sort parameters
#define BKT_SHIFT 9
#define BKT_NODES 512                                    // nodes per bucket
#define N_BKT     ((N_NODES + BKT_NODES - 1) / BKT_NODES)  // 196
#define EBLK      256                                    // edge blocks in P1/P3
#define ECHUNK    ((N_EDGES + EBLK - 1) / EBLK)          // 4883

// ---------------------------------------------------------------------------
// P1: per-edge-block histogram over dst buckets (LDS, no global atomics)
__global__ void k_hist(const int* __restrict__ dst, int* __restrict__ hist) {
    __shared__ int h[N_BKT];
    for (int i = threadIdx.x; i < N_BKT; i += 256) h[i] = 0;
    __syncthreads();
    int e0 = blockIdx.x * ECHUNK, e1 = min(e0 + ECHUNK, N_EDGES);
    for (int e = e0 + threadIdx.x; e < e1; e += 256)
        atomicAdd(&h[dst[e] >> BKT_SHIFT], 1);
    __syncthreads();
    for (int i = threadIdx.x; i < N_BKT; i += 256)
        hist[blockIdx.x * N_BKT + i] = h[i];
}

// P2a: column scan — colscan[B][b] = sum_{B'<B} hist[B'][b]; btot[b] = total
__global__ void k_colscan(const int* __restrict__ hist, int* __restrict__ colscan,
                          int* __restrict__ btot) {
    __shared__ int s[256];
    int b = blockIdx.x;
    int v = hist[threadIdx.x * N_BKT + b];
    s[threadIdx.x] = v;
    __syncthreads();
    for (int off = 1; off < 256; off <<= 1) {
        int t = (threadIdx.x >= off) ? s[threadIdx.x - off] : 0;
        __syncthreads();
        s[threadIdx.x] += t;
        __syncthreads();
    }
    colscan[threadIdx.x * N_BKT + b] = s[threadIdx.x] - v;
    if (threadIdx.x == 255) btot[b] = s[255];
}

// P2b: exclusive scan of bucket totals -> base[0..N_BKT]
__global__ void k_bktbase(const int* __restrict__ btot, int* __restrict__ base) {
    __shared__ int s[256];
    int v = (threadIdx.x < N_BKT) ? btot[threadIdx.x] : 0;
    s[threadIdx.x] = v;
    __syncthreads();
    for (int off = 1; off < 256; off <<= 1) {
        int t = (threadIdx.x >= off) ? s[threadIdx.x - off] : 0;
        __syncthreads();
        s[threadIdx.x] += t;
        __syncthreads();
    }
    if (threadIdx.x < N_BKT) base[threadIdx.x] = s[threadIdx.x] - v;
    if (threadIdx.x == N_BKT - 1) base[N_BKT] = s[threadIdx.x];
}

// P3: scatter edges into bucket-grouped ebuf via LDS cursors
__global__ void k_bktscatter(const int* __restrict__ src, const int* __restrict__ dst,
                             const int* __restrict__ base, const int* __restrict__ colscan,
                             int2* __restrict__ ebuf) {
    __shared__ int cur[N_BKT];
    for (int i = threadIdx.x; i < N_BKT; i += 256)
        cur[i] = base[i] + colscan[blockIdx.x * N_BKT + i];
    __syncthreads();
    int e0 = blockIdx.x * ECHUNK, e1 = min(e0 + ECHUNK, N_EDGES);
    for (int e = e0 + threadIdx.x; e < e1; e += 256) {
        int s = src[e], d = dst[e];
        int pos = atomicAdd(&cur[d >> BKT_SHIFT], 1);
        ebuf[pos] = make_int2(s, d);
    }
}

// P4: per-bucket node fill: degree hist (LDS) -> rowptr + dis (coalesced),
//     then LDS-cursor scatter of src into elist (contiguous region per block).
__global__ void k_bktfill(const int2* __restrict__ ebuf, const int* __restrict__ base,
                          int* __restrict__ rowptr, float* __restrict__ dis,
                          int* __restrict__ elist) {
    __shared__ int cnt_l[BKT_NODES];
    __shared__ int rp_l[BKT_NODES];
    __shared__ int ps[256];
    int b = blockIdx.x, tid = threadIdx.x;
    int n0 = b * BKT_NODES;
    int e0 = base[b], e1 = base[b + 1];
    cnt_l[tid] = 0; cnt_l[tid + 256] = 0;
    __syncthreads();
    for (int e = e0 + tid; e < e1; e += 256)
        atomicAdd(&cnt_l[ebuf[e].y & (BKT_NODES - 1)], 1);
    __syncthreads();
    int a = cnt_l[2 * tid], c = cnt_l[2 * tid + 1];
    int p = a + c;
    ps[tid] = p;
    __syncthreads();
    for (int off = 1; off < 256; off <<= 1) {
        int t = (tid >= off) ? ps[tid - off] : 0;
        __syncthreads();
        ps[tid] += t;
        __syncthreads();
    }
    int bs = ps[tid] - p;                 // exclusive over pairs
    rp_l[2 * tid] = bs;
    rp_l[2 * tid + 1] = bs + a;
    __syncthreads();
#pragma unroll
    for (int k = 0; k < 2; k++) {
        int i = tid + k * 256;
        int node = n0 + i;
        if (node < N_NODES) {
            rowptr[node] = e0 + rp_l[i];
            dis[node] = rsqrtf((float)cnt_l[i] + 1.0f);
        }
    }
    if (b == 0 && tid == 0) rowptr[N_NODES] = N_EDGES;
    __syncthreads();
    cnt_l[tid] = rp_l[tid];               // reuse cnt_l as cursor
    cnt_l[tid + 256] = rp_l[tid + 256];
    __syncthreads();
    for (int e = e0 + tid; e < e1; e += 256) {
        int2 sd = ebuf[e];
        int pos = atomicAdd(&cnt_l[sd.y & (BKT_NODES - 1)], 1);
        elist[e0 + pos] = sd.x;
    }
}

// ---------------------------------------------------------------------------
// xs[n,c] = x[n,c] * dis[n]
__global__ void k_xs(const float* __restrict__ x, const float* __restrict__ dis,
                     float* __restrict__ xs) {
    int t = blockIdx.x * blockDim.x + threadIdx.x;
    if (t >= N_NODES * F_IN) return;
    xs[t] = x[t] * dis[t / F_IN];
}

// 3-channel gather: aggx[n] = dis[n] * ( sum_{s in N(n)} xs[s] + xs[n] )
__global__ void k_aggx(const int* __restrict__ rp, const int* __restrict__ elist,
                       const float* __restrict__ dis, const float* __restrict__ xs,
                       float* __restrict__ aggx) {
    int n = blockIdx.x * blockDim.x + threadIdx.x;
    if (n >= N_NODES) return;
    int start = rp[n], end = rp[n + 1];
    float a0 = 0.f, a1 = 0.f, a2 = 0.f;
    for (int e = start; e < end; e++) {
        int s = elist[e];
        a0 += xs[s * 3 + 0];
        a1 += xs[s * 3 + 1];
        a2 += xs[s * 3 + 2];
    }
    float dn = dis[n];
    aggx[n * 3 + 0] = dn * (a0 + xs[n * 3 + 0]);
    aggx[n * 3 + 1] = dn * (a1 + xs[n * 3 + 1]);
    aggx[n * 3 + 2] = dn * (a2 + xs[n * 3 + 2]);
}

// h1s[n,h] = relu( aggx[n,:] @ W1[:,h] + b1[h] ) * dis[n]
__global__ void k_l1(const float* __restrict__ aggx, const float* __restrict__ W1,
                     const float* __restrict__ b1, const float* __restrict__ dis,
                     float* __restrict__ h1s) {
    int t = blockIdx.x * blockDim.x + threadIdx.x;   // n*64 + h
    if (t >= N_NODES * HIDDEN) return;
    int n = t >> 6, h = t & 63;
    float a0 = aggx[n * 3 + 0], a1 = aggx[n * 3 + 1], a2 = aggx[n * 3 + 2];
    float v = a0 * W1[h] + a1 * W1[HIDDEN + h] + a2 * W1[2 * HIDDEN + h] + b1[h];
    h1s[t] = fmaxf(v, 0.0f) * dis[n];
}

// 64-channel gather: B[n] = dis[n] * ( sum_s h1s[s] + h1s[n] )
__global__ void k_gather64(const int* __restrict__ rp, const int* __restrict__ elist,
                           const float* __restrict__ dis,
                           const float* __restrict__ H, float* __restrict__ OUT) {
    int node = blockIdx.x * 4 + (threadIdx.x >> 6);
    int lane = threadIdx.x & 63;
    if (node >= N_NODES) return;
    int start = rp[node], deg = rp[node + 1] - start;
    int eg  = lane >> 4;     // which of 4 concurrent edges
    int ch4 = lane & 15;     // which float4 of the row
    float4 acc = make_float4(0.f, 0.f, 0.f, 0.f);
    for (int base = 0; base < deg; base += 64) {
        int m = min(64, deg - base);
        int eid = (lane < m) ? elist[start + base + lane] : 0;
        int k = 0;
        for (; k + 4 <= m; k += 4) {
            int s = __shfl(eid, k + eg);
            float4 v = *(const float4*)(H + (size_t)s * HIDDEN + ch4 * 4);
            acc.x += v.x; acc.y += v.y; acc.z += v.z; acc.w += v.w;
        }
        for (; k < m; k++) {
            int s = __shfl(eid, k);
            if (eg == 0) {
                float4 v = *(const float4*)(H + (size_t)s * HIDDEN + ch4 * 4);
                acc.x += v.x; acc.y += v.y; acc.z += v.z; acc.w += v.w;
            }
        }
    }
    acc.x += __shfl_xor(acc.x, 16); acc.y += __shfl_xor(acc.y, 16);
    acc.z += __shfl_xor(acc.z, 16); acc.w += __shfl_xor(acc.w, 16);
    acc.x += __shfl_xor(acc.x, 32); acc.y += __shfl_xor(acc.y, 32);
    acc.z += __shfl_xor(acc.z, 32); acc.w += __shfl_xor(acc.w, 32);
    if (lane < 16) {
        float dn = dis[node];
        float4 self = *(const float4*)(H + (size_t)node * HIDDEN + lane * 4);
        float4 o;
        o.x = dn * (acc.x + self.x);
        o.y = dn * (acc.y + self.y);
        o.z = dn * (acc.z + self.z);
        o.w = dn * (acc.w + self.w);
        *(float4*)(OUT + (size_t)node * HIDDEN + lane * 4) = o;
    }
}

// ---------------------------------------------------------------------------
// graph boundaries from sorted batch: gstart[g] = first node with batch>=g
__global__ void k_gb(const int* __restrict__ batch, int* __restrict__ gstart) {
    int n = blockIdx.x * blockDim.x + threadIdx.x;
    if (n >= N_NODES) return;
    if (n == 0) {
        for (int g = 0; g <= batch[0]; g++) gstart[g] = 0;
    } else {
        int b0 = batch[n - 1], b1 = batch[n];
        for (int g = b0 + 1; g <= b1; g++) gstart[g] = n;
    }
    if (n == N_NODES - 1) {
        for (int g = batch[n] + 1; g <= N_GRAPHS; g++) gstart[g] = N_NODES;
    }
}

// fold head: Wc = W2 @ Wl  [64,5],  bc = b2 @ Wl + bl  [5]
__global__ void k_wc(const float* __restrict__ W2, const float* __restrict__ Wl,
                     const float* __restrict__ b2, const float* __restrict__ bl,
                     float* __restrict__ Wc, float* __restrict__ bc) {
    int t = threadIdx.x;
    if (t < HIDDEN * N_CLASSES) {
        int k = t / N_CLASSES, c = t % N_CLASSES;
        float acc = 0.0f;
#pragma unroll
        for (int j = 0; j < HIDDEN; j++)
            acc = fmaf(W2[k * HIDDEN + j], Wl[j * N_CLASSES + c], acc);
        Wc[t] = acc;
    } else if (t < HIDDEN * N_CLASSES + N_CLASSES) {
        int c = t - HIDDEN * N_CLASSES;
        float acc = bl[c];
#pragma unroll
        for (int j = 0; j < HIDDEN; j++)
            acc = fmaf(b2[j], Wl[j * N_CLASSES + c], acc);
        bc[c] = acc;
    }
}

// fused pool+head: one block per graph; 4 waves stride the node range,
// LDS-reduce, then out[g,c] = (gsum @ Wc[:,c]) / max(cnt,1) + bc[c]
__global__ void k_poolhead(const float* __restrict__ H2, const int* __restrict__ gstart,
                           const float* __restrict__ Wc, const float* __restrict__ bc,
                           float* __restrict__ out) {
    __shared__ float part[4][HIDDEN];
    __shared__ float gl[HIDDEN];
    int g = blockIdx.x;
    int s = gstart[g], e = gstart[g + 1];
    int c = threadIdx.x & 63, w = threadIdx.x >> 6;
    float acc = 0.0f;
    for (int n = s + w; n < e; n += 4)
        acc += H2[(size_t)n * HIDDEN + c];
    part[w][c] = acc;
    __syncthreads();
    if (threadIdx.x < HIDDEN)
        gl[threadIdx.x] = part[0][threadIdx.x] + part[1][threadIdx.x] +
                          part[2][threadIdx.x] + part[3][threadIdx.x];
    __syncthreads();
    if (threadIdx.x < N_CLASSES) {
        int cc = threadIdx.x;
        float cntf = fmaxf((float)(e - s), 1.0f);
        float dot = 0.0f;
#pragma unroll
        for (int k = 0; k < HIDDEN; k++)
            dot = fmaf(gl[k], Wc[k * N_CLASSES + cc], dot);
        out[g * N_CLASSES + cc] = dot / cntf + bc[cc];
    }
}

// ---------------------------------------------------------------------------
extern "C" void kernel_launch(void* const* d_in, const int* in_sizes, int n_in,
                              void* d_out, int out_size, void* d_ws, size_t ws_size,
                              hipStream_t stream) {
    const float* x     = (const float*)d_in[0];
    const int*   ei    = (const int*)  d_in[1];   // [2, N_EDGES] flat: src then dst
    const int*   batch = (const int*)  d_in[2];
    const float* W1    = (const float*)d_in[3];
    const float* b1    = (const float*)d_in[4];
    const float* W2    = (const float*)d_in[5];
    const float* b2    = (const float*)d_in[6];
    const float* Wl    = (const float*)d_in[7];
    const float* bl    = (const float*)d_in[8];
    float* out = (float*)d_out;

    const int* src = ei;
    const int* dst = ei + N_EDGES;

    // workspace layout (4B units; ebuf first for 8B alignment)
    int2*  ebuf    = (int2*)d_ws;                        // E int2
    int*   elist   = (int*)(ebuf + N_EDGES);             // E
    int*   hist    = elist + N_EDGES;                    // EBLK*N_BKT
    int*   colscan = hist + EBLK * N_BKT;                // EBLK*N_BKT
    int*   btot    = colscan + EBLK * N_BKT;             // N_BKT
    int*   base    = btot + N_BKT;                       // N_BKT+1
    int*   rowptr  = base + N_BKT + 1;                   // N+1
    float* dis     = (float*)(rowptr + N_NODES + 1);     // N
    float* xs      = dis + N_NODES;                      // N*3
    float* aggx    = xs + (size_t)N_NODES * F_IN;        // N*3
    float* h1s     = aggx + (size_t)N_NODES * F_IN;      // N*64
    float* B       = h1s + (size_t)N_NODES * HIDDEN;     // N*64
    int*   gstart  = (int*)(B + (size_t)N_NODES * HIDDEN); // N_GRAPHS+1
    float* Wc      = (float*)(gstart + N_GRAPHS + 1);    // 64*5
    float* bc      = Wc + HIDDEN * N_CLASSES;            // 5

    const int BS = 256;
    const int g_nodes  = (N_NODES + BS - 1) / BS;
    const int g_nh     = (N_NODES * HIDDEN + BS - 1) / BS;
    const int g_n3     = (N_NODES * F_IN + BS - 1) / BS;
    const int g_gather = (N_NODES + 3) / 4;

    // CSR build: two-level counting sort, no global atomics
    k_hist<<<EBLK, 256, 0, stream>>>(dst, hist);
    k_colscan<<<N_BKT, 256, 0, stream>>>(hist, colscan, btot);
    k_bktbase<<<1, 256, 0, stream>>>(btot, base);
    k_bktscatter<<<EBLK, 256, 0, stream>>>(src, dst, base, colscan, ebuf);
    k_bktfill<<<N_BKT, 256, 0, stream>>>(ebuf, base, rowptr, dis, elist);

    // independent tiny precomputes
    k_wc<<<1, 384, 0, stream>>>(W2, Wl, b2, bl, Wc, bc);
    k_gb<<<g_nodes, BS, 0, stream>>>(batch, gstart);

    // layer 1 in input space
    k_xs<<<g_n3, BS, 0, stream>>>(x, dis, xs);
    k_aggx<<<g_nodes, BS, 0, stream>>>(rowptr, elist, dis, xs, aggx);
    k_l1<<<g_nh, BS, 0, stream>>>(aggx, W1, b1, dis, h1s);

    // layer 2 aggregation (W2 folded into head)
    k_gather64<<<g_gather, BS, 0, stream>>>(rowptr, elist, dis, h1s, B);

    // fused pool + head
    k_poolhead<<<N_GRAPHS, 256, 0, stream>>>(B, gstart, Wc, bc, out);
}

// Round 6
// 206.947 us; speedup vs baseline: 12.4175x; 1.1363x over previous
//
#include <hip/hip_runtime.h>
#include <hip/hip_bf16.h>

#define N_NODES   100000
#define N_EDGES   1250000
#define N_GRAPHS  512
#define HIDDEN    64
#define F_IN      3
#define N_CLASSES 5

// bucket sort parameters
#define BKT_SHIFT 9
#define BKT_NODES 512                                    // nodes per bucket
#define N_BKT     ((N_NODES + BKT_NODES - 1) / BKT_NODES)  // 196
#define EBLK      256                                    // edge blocks in P1/P3
#define ECHUNK    ((N_EDGES + EBLK - 1) / EBLK)          // 4883

// bf16 helpers (RNE; inputs are finite)
__device__ __forceinline__ unsigned short f2bf(float f) {
    unsigned u = __float_as_uint(f);
    u += 0x7FFF + ((u >> 16) & 1);
    return (unsigned short)(u >> 16);
}

// ---------------------------------------------------------------------------
// P1: per-edge-block histogram over dst buckets (LDS, no global atomics)
__global__ void k_hist(const int* __restrict__ dst, int* __restrict__ hist) {
    __shared__ int h[N_BKT];
    for (int i = threadIdx.x; i < N_BKT; i += 256) h[i] = 0;
    __syncthreads();
    int e0 = blockIdx.x * ECHUNK, e1 = min(e0 + ECHUNK, N_EDGES);
    for (int e = e0 + threadIdx.x; e < e1; e += 256)
        atomicAdd(&h[dst[e] >> BKT_SHIFT], 1);
    __syncthreads();
    for (int i = threadIdx.x; i < N_BKT; i += 256)
        hist[blockIdx.x * N_BKT + i] = h[i];
}

// P2a: column scan — colscan[B][b] = sum_{B'<B} hist[B'][b]; btot[b] = total
__global__ void k_colscan(const int* __restrict__ hist, int* __restrict__ colscan,
                          int* __restrict__ btot) {
    __shared__ int s[256];
    int b = blockIdx.x;
    int v = hist[threadIdx.x * N_BKT + b];
    s[threadIdx.x] = v;
    __syncthreads();
    for (int off = 1; off < 256; off <<= 1) {
        int t = (threadIdx.x >= off) ? s[threadIdx.x - off] : 0;
        __syncthreads();
        s[threadIdx.x] += t;
        __syncthreads();
    }
    colscan[threadIdx.x * N_BKT + b] = s[threadIdx.x] - v;
    if (threadIdx.x == 255) btot[b] = s[255];
}

// P2b: exclusive scan of bucket totals -> base[0..N_BKT]
__global__ void k_bktbase(const int* __restrict__ btot, int* __restrict__ base) {
    __shared__ int s[256];
    int v = (threadIdx.x < N_BKT) ? btot[threadIdx.x] : 0;
    s[threadIdx.x] = v;
    __syncthreads();
    for (int off = 1; off < 256; off <<= 1) {
        int t = (threadIdx.x >= off) ? s[threadIdx.x - off] : 0;
        __syncthreads();
        s[threadIdx.x] += t;
        __syncthreads();
    }
    if (threadIdx.x < N_BKT) base[threadIdx.x] = s[threadIdx.x] - v;
    if (threadIdx.x == N_BKT - 1) base[N_BKT] = s[threadIdx.x];
}

// P3: scatter edges into bucket-grouped ebuf via LDS cursors
__global__ void k_bktscatter(const int* __restrict__ src, const int* __restrict__ dst,
                             const int* __restrict__ base, const int* __restrict__ colscan,
                             int2* __restrict__ ebuf) {
    __shared__ int cur[N_BKT];
    for (int i = threadIdx.x; i < N_BKT; i += 256)
        cur[i] = base[i] + colscan[blockIdx.x * N_BKT + i];
    __syncthreads();
    int e0 = blockIdx.x * ECHUNK, e1 = min(e0 + ECHUNK, N_EDGES);
    for (int e = e0 + threadIdx.x; e < e1; e += 256) {
        int s = src[e], d = dst[e];
        int pos = atomicAdd(&cur[d >> BKT_SHIFT], 1);
        ebuf[pos] = make_int2(s, d);
    }
}

// P4: per-bucket node fill: degree hist (LDS) -> rowptr + dis + xs4 (coalesced),
//     then LDS-cursor scatter of src into elist (contiguous region per block).
__global__ void k_bktfill(const int2* __restrict__ ebuf, const int* __restrict__ base,
                          const float* __restrict__ x,
                          int* __restrict__ rowptr, float* __restrict__ dis,
                          uint2* __restrict__ xs4, int* __restrict__ elist) {
    __shared__ int cnt_l[BKT_NODES];
    __shared__ int rp_l[BKT_NODES];
    __shared__ int ps[256];
    int b = blockIdx.x, tid = threadIdx.x;
    int n0 = b * BKT_NODES;
    int e0 = base[b], e1 = base[b + 1];
    cnt_l[tid] = 0; cnt_l[tid + 256] = 0;
    __syncthreads();
    for (int e = e0 + tid; e < e1; e += 256)
        atomicAdd(&cnt_l[ebuf[e].y & (BKT_NODES - 1)], 1);
    __syncthreads();
    int a = cnt_l[2 * tid], c = cnt_l[2 * tid + 1];
    int p = a + c;
    ps[tid] = p;
    __syncthreads();
    for (int off = 1; off < 256; off <<= 1) {
        int t = (tid >= off) ? ps[tid - off] : 0;
        __syncthreads();
        ps[tid] += t;
        __syncthreads();
    }
    int bs = ps[tid] - p;                 // exclusive over pairs
    rp_l[2 * tid] = bs;
    rp_l[2 * tid + 1] = bs + a;
    __syncthreads();
#pragma unroll
    for (int k = 0; k < 2; k++) {
        int i = tid + k * 256;
        int node = n0 + i;
        if (node < N_NODES) {
            rowptr[node] = e0 + rp_l[i];
            float dv = rsqrtf((float)cnt_l[i] + 1.0f);
            dis[node] = dv;
            float x0 = x[node * 3 + 0], x1 = x[node * 3 + 1], x2 = x[node * 3 + 2];
            xs4[node] = make_uint2((unsigned)f2bf(x0 * dv) |
                                   ((unsigned)f2bf(x1 * dv) << 16),
                                   (unsigned)f2bf(x2 * dv));
        }
    }
    if (b == 0 && tid == 0) rowptr[N_NODES] = N_EDGES;
    __syncthreads();
    cnt_l[tid] = rp_l[tid];               // reuse cnt_l as cursor
    cnt_l[tid + 256] = rp_l[tid + 256];
    __syncthreads();
    for (int e = e0 + tid; e < e1; e += 256) {
        int2 sd = ebuf[e];
        int pos = atomicAdd(&cnt_l[sd.y & (BKT_NODES - 1)], 1);
        elist[e0 + pos] = sd.x;
    }
}

// ---------------------------------------------------------------------------
// 3-channel gather (bf16 source rows): aggx[n] = dis[n]*( sum_s xs[s] + xs[n] )
__global__ void k_aggx(const int* __restrict__ rp, const int* __restrict__ elist,
                       const float* __restrict__ dis, const uint2* __restrict__ xs4,
                       float* __restrict__ aggx) {
    int n = blockIdx.x * blockDim.x + threadIdx.x;
    if (n >= N_NODES) return;
    int start = rp[n], end = rp[n + 1];
    float a0 = 0.f, a1 = 0.f, a2 = 0.f;
    for (int e = start; e < end; e++) {
        int s = elist[e];
        uint2 u = xs4[s];
        a0 += __uint_as_float(u.x << 16);
        a1 += __uint_as_float(u.x & 0xFFFF0000u);
        a2 += __uint_as_float(u.y << 16);
    }
    uint2 un = xs4[n];
    float dn = dis[n];
    aggx[n * 3 + 0] = dn * (a0 + __uint_as_float(un.x << 16));
    aggx[n * 3 + 1] = dn * (a1 + __uint_as_float(un.x & 0xFFFF0000u));
    aggx[n * 3 + 2] = dn * (a2 + __uint_as_float(un.y << 16));
}

// h1b[n,h] = bf16( relu( aggx[n,:] @ W1[:,h] + b1[h] ) * dis[n] )
__global__ void k_l1(const float* __restrict__ aggx, const float* __restrict__ W1,
                     const float* __restrict__ b1, const float* __restrict__ dis,
                     unsigned short* __restrict__ h1b) {
    int t = blockIdx.x * blockDim.x + threadIdx.x;   // n*64 + h
    if (t >= N_NODES * HIDDEN) return;
    int n = t >> 6, h = t & 63;
    float a0 = aggx[n * 3 + 0], a1 = aggx[n * 3 + 1], a2 = aggx[n * 3 + 2];
    float v = a0 * W1[h] + a1 * W1[HIDDEN + h] + a2 * W1[2 * HIDDEN + h] + b1[h];
    h1b[t] = f2bf(fmaxf(v, 0.0f) * dis[n]);
}

// 64-channel gather (bf16 rows): B[n] = dis[n] * ( sum_s h1[s] + h1[n] )
__global__ void k_gather64(const int* __restrict__ rp, const int* __restrict__ elist,
                           const float* __restrict__ dis,
                           const unsigned short* __restrict__ Hb,
                           float* __restrict__ OUT) {
    int node = blockIdx.x * 4 + (threadIdx.x >> 6);
    int lane = threadIdx.x & 63;
    if (node >= N_NODES) return;
    int start = rp[node], deg = rp[node + 1] - start;
    int eg  = lane >> 4;     // which of 4 concurrent edges
    int ch4 = lane & 15;     // which bf16-quad of the row
    float4 acc = make_float4(0.f, 0.f, 0.f, 0.f);
    for (int base = 0; base < deg; base += 64) {
        int m = min(64, deg - base);
        int eid = (lane < m) ? elist[start + base + lane] : 0;
        int k = 0;
        for (; k + 4 <= m; k += 4) {
            int s = __shfl(eid, k + eg);
            uint2 u = *(const uint2*)(Hb + ((size_t)s << 6) + (ch4 << 2));
            acc.x += __uint_as_float(u.x << 16);
            acc.y += __uint_as_float(u.x & 0xFFFF0000u);
            acc.z += __uint_as_float(u.y << 16);
            acc.w += __uint_as_float(u.y & 0xFFFF0000u);
        }
        for (; k < m; k++) {
            int s = __shfl(eid, k);
            if (eg == 0) {
                uint2 u = *(const uint2*)(Hb + ((size_t)s << 6) + (ch4 << 2));
                acc.x += __uint_as_float(u.x << 16);
                acc.y += __uint_as_float(u.x & 0xFFFF0000u);
                acc.z += __uint_as_float(u.y << 16);
                acc.w += __uint_as_float(u.y & 0xFFFF0000u);
            }
        }
    }
    acc.x += __shfl_xor(acc.x, 16); acc.y += __shfl_xor(acc.y, 16);
    acc.z += __shfl_xor(acc.z, 16); acc.w += __shfl_xor(acc.w, 16);
    acc.x += __shfl_xor(acc.x, 32); acc.y += __shfl_xor(acc.y, 32);
    acc.z += __shfl_xor(acc.z, 32); acc.w += __shfl_xor(acc.w, 32);
    if (lane < 16) {
        float dn = dis[node];
        uint2 u = *(const uint2*)(Hb + ((size_t)node << 6) + (lane << 2));
        float4 o;
        o.x = dn * (acc.x + __uint_as_float(u.x << 16));
        o.y = dn * (acc.y + __uint_as_float(u.x & 0xFFFF0000u));
        o.z = dn * (acc.z + __uint_as_float(u.y << 16));
        o.w = dn * (acc.w + __uint_as_float(u.y & 0xFFFF0000u));
        *(float4*)(OUT + (size_t)node * HIDDEN + lane * 4) = o;
    }
}

// ---------------------------------------------------------------------------
// merged tiny precomputes: block 0 folds the head (Wc = W2@Wl, bc = b2@Wl+bl);
// blocks >=1 fill graph boundaries gstart from the sorted batch vector.
__global__ void k_misc(const float* __restrict__ W2, const float* __restrict__ Wl,
                       const float* __restrict__ b2, const float* __restrict__ bl,
                       const int* __restrict__ batch,
                       float* __restrict__ Wc, float* __restrict__ bc,
                       int* __restrict__ gstart) {
    if (blockIdx.x == 0) {
        for (int t = threadIdx.x; t < HIDDEN * N_CLASSES + N_CLASSES; t += 256) {
            if (t < HIDDEN * N_CLASSES) {
                int k = t / N_CLASSES, c = t % N_CLASSES;
                float acc = 0.0f;
#pragma unroll
                for (int j = 0; j < HIDDEN; j++)
                    acc = fmaf(W2[k * HIDDEN + j], Wl[j * N_CLASSES + c], acc);
                Wc[t] = acc;
            } else {
                int c = t - HIDDEN * N_CLASSES;
                float acc = bl[c];
#pragma unroll
                for (int j = 0; j < HIDDEN; j++)
                    acc = fmaf(b2[j], Wl[j * N_CLASSES + c], acc);
                bc[c] = acc;
            }
        }
        return;
    }
    int n = (blockIdx.x - 1) * 256 + threadIdx.x;
    if (n >= N_NODES) return;
    if (n == 0) {
        for (int g = 0; g <= batch[0]; g++) gstart[g] = 0;
    } else {
        int b0 = batch[n - 1], b1 = batch[n];
        for (int g = b0 + 1; g <= b1; g++) gstart[g] = n;
    }
    if (n == N_NODES - 1) {
        for (int g = batch[n] + 1; g <= N_GRAPHS; g++) gstart[g] = N_NODES;
    }
}

// fused pool+head: one block (8 waves) per graph; LDS-reduce,
// then out[g,c] = (gsum @ Wc[:,c]) / max(cnt,1) + bc[c]
__global__ void k_poolhead(const float* __restrict__ H2, const int* __restrict__ gstart,
                           const float* __restrict__ Wc, const float* __restrict__ bc,
                           float* __restrict__ out) {
    __shared__ float part[8][HIDDEN];
    __shared__ float gl[HIDDEN];
    int g = blockIdx.x;
    int s = gstart[g], e = gstart[g + 1];
    int c = threadIdx.x & 63, w = threadIdx.x >> 6;
    float acc = 0.0f;
    for (int n = s + w; n < e; n += 8)
        acc += H2[(size_t)n * HIDDEN + c];
    part[w][c] = acc;
    __syncthreads();
    if (threadIdx.x < HIDDEN) {
        float t = 0.0f;
#pragma unroll
        for (int k = 0; k < 8; k++) t += part[k][threadIdx.x];
        gl[threadIdx.x] = t;
    }
    __syncthreads();
    if (threadIdx.x < N_CLASSES) {
        int cc = threadIdx.x;
        float cntf = fmaxf((float)(e - s), 1.0f);
        float dot = 0.0f;
#pragma unroll
        for (int k = 0; k < HIDDEN; k++)
            dot = fmaf(gl[k], Wc[k * N_CLASSES + cc], dot);
        out[g * N_CLASSES + cc] = dot / cntf + bc[cc];
    }
}

// ---------------------------------------------------------------------------
extern "C" void kernel_launch(void* const* d_in, const int* in_sizes, int n_in,
                              void* d_out, int out_size, void* d_ws, size_t ws_size,
                              hipStream_t stream) {
    const float* x     = (const float*)d_in[0];
    const int*   ei    = (const int*)  d_in[1];   // [2, N_EDGES] flat: src then dst
    const int*   batch = (const int*)  d_in[2];
    const float* W1    = (const float*)d_in[3];
    const float* b1    = (const float*)d_in[4];
    const float* W2    = (const float*)d_in[5];
    const float* b2    = (const float*)d_in[6];
    const float* Wl    = (const float*)d_in[7];
    const float* bl    = (const float*)d_in[8];
    float* out = (float*)d_out;

    const int* src = ei;
    const int* dst = ei + N_EDGES;

    // workspace layout (4B units; ebuf first for 8B alignment; pads keep
    // xs4/h1b 8B-aligned and B 16B-aligned)
    int2*  ebuf    = (int2*)d_ws;                        // E int2
    int*   elist   = (int*)(ebuf + N_EDGES);             // E
    int*   hist    = elist + N_EDGES;                    // EBLK*N_BKT
    int*   colscan = hist + EBLK * N_BKT;                // EBLK*N_BKT
    int*   btot    = colscan + EBLK * N_BKT;             // N_BKT
    int*   base    = btot + N_BKT;                       // N_BKT+1 (197)
    int*   rowptr  = base + N_BKT + 1;                   // N+1 (+1 pad)
    float* dis     = (float*)(rowptr + N_NODES + 2);     // N (+1 pad)
    uint2* xs4     = (uint2*)(dis + N_NODES + 1);        // N uint2 (8B-aligned)
    float* aggx    = (float*)(xs4 + N_NODES);            // N*3 (+1 pad)
    unsigned short* h1b = (unsigned short*)(aggx + (size_t)N_NODES * F_IN + 1); // N*64 bf16
    float* B       = (float*)(h1b + (size_t)N_NODES * HIDDEN);  // N*64 f32
    int*   gstart  = (int*)(B + (size_t)N_NODES * HIDDEN); // N_GRAPHS+1
    float* Wc      = (float*)(gstart + N_GRAPHS + 1);    // 64*5
    float* bc      = Wc + HIDDEN * N_CLASSES;            // 5

    const int BS = 256;
    const int g_nodes  = (N_NODES + BS - 1) / BS;
    const int g_nh     = (N_NODES * HIDDEN + BS - 1) / BS;
    const int g_gather = (N_NODES + 3) / 4;

    // CSR build: two-level counting sort, no global atomics
    k_hist<<<EBLK, 256, 0, stream>>>(dst, hist);
    k_colscan<<<N_BKT, 256, 0, stream>>>(hist, colscan, btot);
    k_bktbase<<<1, 256, 0, stream>>>(btot, base);
    k_bktscatter<<<EBLK, 256, 0, stream>>>(src, dst, base, colscan, ebuf);
    k_bktfill<<<N_BKT, 256, 0, stream>>>(ebuf, base, x, rowptr, dis, xs4, elist);

    // tiny precomputes (head fold + graph boundaries)
    k_misc<<<g_nodes + 1, 256, 0, stream>>>(W2, Wl, b2, bl, batch, Wc, bc, gstart);

    // layer 1 in input space (bf16 xs rows)
    k_aggx<<<g_nodes, BS, 0, stream>>>(rowptr, elist, dis, xs4, aggx);
    k_l1<<<g_nh, BS, 0, stream>>>(aggx, W1, b1, dis, h1b);

    // layer 2 aggregation (bf16 rows; W2 folded into head)
    k_gather64<<<g_gather, BS, 0, stream>>>(rowptr, elist, dis, h1b, B);

    // fused pool + head
    k_poolhead<<<N_GRAPHS, 512, 0, stream>>>(B, gstart, Wc, bc, out);
}